// Round 6
// baseline (318.090 us; speedup 1.0000x reference)
//
#include <hip/hip_runtime.h>

// LSTM B=65536, L=6, H=50, T=3, IN=3, FC 50->1 — fp16 MFMA, R13.
//
// R13 vs R8-R12 (all 143-153us, VALUBusy pinned 43-47% across occ 41-79%):
// the n-partitioned family is limited by barrier lockstep (phase-locked
// blocks, per-pipe convoys), not by occupancy or issue volume. R13 removes
// ALL barriers:
//  - Wave-private recurrence: one wave owns 32 samples (2 m-tiles) and
//    computes all 13 live n-tiles itself. W = 13x4 half8 frags = 208 VGPR,
//    held in registers; 1 wave/SIMD (launch_bounds(64,1), ~290/512 regs).
//  - h_t rearrangement (acc-layout -> B-frag layout) via wave-private LDS
//    ring-5 (23KB/block); same-wave DS ops are in-order + compiler lgkmcnt
//    -> NO __syncthreads anywhere.
//  - Per step: 8 ds_read_b128 + 104 MFMA + 26 ACT chains (260 trans),
//    26 independent tile-chains of ILP -> scheduler interleaves MFMA/trans/
//    VALU from one wave; no lockstep idle. 4 blocks/CU, grid 2048 = 2 rounds.
//  - W reloaded per layer from wbuf (52 dwordx4, L2-resident 393KB total).
//  - Same MFMA accumulation order (x slab0, x slab1, h slab0, h slab1) and
//    ACT ops as R12 -> bitwise-identical numerics.
// Layout: gates^T = W*X^T, n = 4j+gate; lane (q,lm) holds all 4 gates of
// units j = 4i+q (i=0..12), samples mt*16+lm.

namespace {

constexpr int H  = 50;
constexpr int L  = 6;
constexpr int T  = 3;
constexpr int IN = 3;
constexpr int MW = 32;     // samples per wave (2 m-tiles)
constexpr int ROWS = 72;   // _Float16 row stride (144 B)
constexpr int NSLOT = 5;   // LDS ring slots
constexpr int NT = 13;     // live n-tiles (units 0..51, j>=50 masked)

using half8  = __attribute__((ext_vector_type(8))) _Float16;
using half2v = __attribute__((ext_vector_type(2))) _Float16;
using f32x4  = __attribute__((ext_vector_type(4))) float;

__device__ __forceinline__ float rcp_(float x) { return __builtin_amdgcn_rcpf(x); }
__device__ __forceinline__ float ex2(float x)  { return __builtin_amdgcn_exp2f(x); }

// ---------------- prologue: pack fp16 A-fragments, prescaled ----------------
// frag id f = (l*4 + s)*16 + nt ; lane's frag: W[n=16*nt+(lam&15)][k=32*s+(lam>>4)*8+jj]
// Rows prescaled: gate g (n&3==2) by 2/ln2, others by 1/ln2 (bias included).
__global__ void wprep(const float* __restrict__ w_ih0, const float* __restrict__ w_ihL,
                      const float* __restrict__ w_hh,  const float* __restrict__ b_ih,
                      const float* __restrict__ b_hh,  _Float16* __restrict__ wbuf) {
  int t = blockIdx.x * 256 + threadIdx.x;
  if (t >= 384 * 64) return;
  int lam = t & 63, f = t >> 6;
  int nt = f & 15, s = (f >> 4) & 3, l = f >> 6;
  int n = nt * 16 + (lam & 15);
  int j = n >> 2, gate = n & 3, row = gate * 50 + j;  // PyTorch gate order i,f,g,o
  float scale = (gate == 2) ? 2.8853900817779268f : 1.4426950408889634f;
  _Float16 o8[8];
#pragma unroll
  for (int jj = 0; jj < 8; ++jj) {
    int k = s * 32 + (lam >> 4) * 8 + jj;
    float v = 0.f;
    if (j < H) {
      if (s < 2) {                       // x-part, k in [0,64)
        int ksz = (l == 0) ? IN : H;
        if (k < ksz) v = (l == 0) ? w_ih0[row * IN + k]
                                  : w_ihL[((size_t)(l - 1) * 200 + row) * H + k];
      } else {                           // h-part
        int kh = k - 64;
        if (kh < H)        v = w_hh[((size_t)l * 200 + row) * H + kh];
        else if (kh == 63) v = b_ih[l * 200 + row] + b_hh[l * 200 + row];  // bias
      }
    }
    o8[jj] = (_Float16)(v * scale);
  }
  ((half8*)wbuf)[t] = *(half8*)o8;
}

// ---------------- main kernel: one wave per block, barrier-free ----------------
__global__ __launch_bounds__(64, 1)
void lstm_wave(const float* __restrict__ x,   const float* __restrict__ h0,
               const float* __restrict__ c0,  const float* __restrict__ fc_w,
               const float* __restrict__ fc_b, const _Float16* __restrict__ wbuf,
               float* __restrict__ out, int B) {
  const int lam = threadIdx.x;            // 0..63
  const int q   = lam >> 4;
  const int lm  = lam & 15;
  const int bbase = blockIdx.x * MW;

  __shared__ __align__(16) _Float16 ys[NSLOT][MW][ROWS];   // 23040 B

  // ---- once-only invariant: cols [50,62]=0, col 63=1.0 in ALL slots.
  //      (h/h0/x writes only touch k<50 -> holds forever) ----
  for (int r = lam; r < NSLOT * MW; r += 64) {
    _Float16* row = &ys[0][0][0] + (size_t)r * ROWS;
#pragma unroll
    for (int z = 0; z < 6; ++z)
      *(unsigned int*)(row + 50 + 2 * z) = 0u;            // cols 50..61
    half2v pb; pb[0] = (_Float16)0.f; pb[1] = (_Float16)1.f;
    *(half2v*)(row + 62) = pb;                            // 62=0, 63=1.0
  }
  // ---- x staging into slots 2,3,4 (= sigma(-1,t)): k<3 data, [3,32) zero ----
  for (int r = lam; r < T * MW; r += 64) {
    const int t = r >> 5, m = r & 31;
    const float* xs = x + (size_t)(bbase + m) * (IN * T) + t;
    _Float16* row = &ys[2 + t][m][0];
    half2v p0; p0[0] = (_Float16)xs[0]; p0[1] = (_Float16)xs[3];
    half2v p1; p1[0] = (_Float16)xs[6]; p1[1] = (_Float16)0.f;
    *(half2v*)(row)     = p0;
    *(half2v*)(row + 2) = p1;
#pragma unroll
    for (int z = 0; z < 7; ++z)              // k in [4,32) := 0 (layer-0 slab-0 pad)
      *(unsigned long long*)(row + 4 + 4 * z) = 0ull;
  }
  // no barrier: single-wave block; DS pipe is in-order per wave.

  half8 W[NT][4];                            // 208 VGPR — the whole layer's weights
  float cc[2][NT];                           // 26 — cell state
  const f32x4 z4 = {0.f, 0.f, 0.f, 0.f};

  int sh0 = 0;                               // h0 slot for layer l = (4l)%5
#pragma unroll 1
  for (int l = 0; l < L; ++l) {
    const int p0 = sh0;
    const int p1 = (sh0 + 1) % 5, p2 = (sh0 + 2) % 5;
    const int p3 = (sh0 + 3) % 5, p4 = (sh0 + 4) % 5;

    // ---- W fragments for this layer (52 coalesced dwordx4, L2-resident) ----
#pragma unroll
    for (int i = 0; i < NT; ++i)
#pragma unroll
      for (int s = 0; s < 4; ++s)
        W[i][s] = ((const half8*)wbuf)[((l * 4 + s) * 16 + i) * 64 + lam];
    // ---- c0 straight to registers ----
#pragma unroll
    for (int mt = 0; mt < 2; ++mt)
#pragma unroll
      for (int i = 0; i < NT; ++i) {
        const int j = 4 * i + q;
        cc[mt][i] = (j < H)
            ? c0[((size_t)l * B + bbase + mt * 16 + lm) * H + j] : 0.f;
      }
    // ---- stage h0 into slot p0 (32 rows x 25 half2 pairs, 2 lanes/row) ----
    {
      const int row = lam >> 1;
      const int kp0 = (lam & 1) * 13;
      const float* hp = h0 + ((size_t)l * B + bbase + row) * H;
#pragma unroll
      for (int p = 0; p < 13; ++p) {
        const int kp = kp0 + p;
        if (kp < 25) {
          float2 v = *(const float2*)(hp + 2 * kp);
          half2v pv; pv[0] = (_Float16)v.x; pv[1] = (_Float16)v.y;
          *(half2v*)(&ys[p0][row][2 * kp]) = pv;
        }
      }
    }

    // ---- T steps, barrier-free: same-wave write->read ordering via lgkmcnt --
#pragma unroll
    for (int t = 0; t < T; ++t) {
      const int shs = (t == 0) ? p0 : ((t == 1) ? p1 : p2);  // h-source slot
      const int sot = (t == 0) ? p1 : ((t == 1) ? p2 : p3);  // h-dest slot
      const int sxt = (t == 0) ? p2 : ((t == 1) ? p3 : p4);  // x-source slot

      // B-fragments up-front (8 ds_read_b128; shared across all 13 n-tiles)
      half8 X0[2], X1[2], Hf0[2], Hf1[2];
#pragma unroll
      for (int mt = 0; mt < 2; ++mt) {
        const _Float16* xb = &ys[sxt][mt * 16 + lm][q * 8];
        X0[mt] = *(const half8*)xb;
        if (l > 0) X1[mt] = *(const half8*)(xb + 32);   // l=0 slab1 W==0: skip
        const _Float16* hb = &ys[shs][mt * 16 + lm][q * 8];
        Hf0[mt] = *(const half8*)hb;
        Hf1[mt] = *(const half8*)(hb + 32);
      }
      // 26 independent tile-chains: 4 MFMA -> ACT -> 1 ds_write_b16 each;
      // scheduler interleaves MFMA / trans / VALU freely (no barriers).
#pragma unroll
      for (int mt = 0; mt < 2; ++mt)
#pragma unroll
        for (int i = 0; i < NT; ++i) {
          f32x4 a = __builtin_amdgcn_mfma_f32_16x16x32_f16(W[i][0], X0[mt], z4, 0, 0, 0);
          if (l > 0)
            a = __builtin_amdgcn_mfma_f32_16x16x32_f16(W[i][1], X1[mt], a, 0, 0, 0);
          a = __builtin_amdgcn_mfma_f32_16x16x32_f16(W[i][2], Hf0[mt], a, 0, 0, 0);
          a = __builtin_amdgcn_mfma_f32_16x16x32_f16(W[i][3], Hf1[mt], a, 0, 0, 0);
          // activations: prescaled gates -> sigm = rcp(1+exp2(-g))
          const float ig = rcp_(1.f + ex2(-a[0]));
          const float fg = rcp_(1.f + ex2(-a[1]));
          const float gg = 2.f * rcp_(1.f + ex2(-a[2])) - 1.f;
          const float og = rcp_(1.f + ex2(-a[3]));
          const float cv = fg * cc[mt][i] + ig * gg;
          cc[mt][i] = cv;
          const float tc = 2.f * rcp_(1.f + ex2(-2.8853900817779268f * cv)) - 1.f;
          const int j = 4 * i + q;
          if (j < H)                          // pad cols (and k63=1.0) stay intact
            ys[sot][mt * 16 + lm][j] = (_Float16)(og * tc);
        }
    }
    sh0 = (sh0 == 0) ? 4 : sh0 - 1;          // (4(l+1))%5
  }

  // ---- fc tail: out[b] = fc_w · h_last + fc_b ; final h slot = 3 ----
  {
    const int m = lam >> 1, strip = lam & 1;
    float part = 0.f;
#pragma unroll
    for (int jj = 0; jj < 25; ++jj) {
      const int jf = 2 * jj + strip;         // 0..49, all < H
      part += fc_w[jf] * (float)ys[3][m][jf];
    }
    part += __shfl_xor(part, 1);
    if (strip == 0) out[bbase + m] = part + fc_b[0];
  }
}

}  // namespace

extern "C" void kernel_launch(void* const* d_in, const int* in_sizes, int n_in,
                              void* d_out, int out_size, void* d_ws, size_t ws_size,
                              hipStream_t stream) {
  const float* x     = (const float*)d_in[0];
  const float* h0    = (const float*)d_in[1];
  const float* c0    = (const float*)d_in[2];
  const float* w_ih0 = (const float*)d_in[3];
  const float* w_ih  = (const float*)d_in[4];
  const float* w_hh  = (const float*)d_in[5];
  const float* b_ih  = (const float*)d_in[6];
  const float* b_hh  = (const float*)d_in[7];
  const float* fc_w  = (const float*)d_in[8];
  const float* fc_b  = (const float*)d_in[9];
  float* out         = (float*)d_out;

  const int B = in_sizes[0] / (IN * T);  // 65536
  _Float16* wbuf = (_Float16*)d_ws;      // 384 frags * 64 lanes * 16 B = 393 KB

  wprep<<<(384 * 64 + 255) / 256, 256, 0, stream>>>(w_ih0, w_ih, w_hh, b_ih, b_hh, wbuf);
  lstm_wave<<<B / MW, 64, 0, stream>>>(x, h0, c0, fc_w, fc_b, wbuf, out, B);
}

// Round 7
// 280.244 us; speedup vs baseline: 1.1350x; 1.1350x over previous
//
#include <hip/hip_runtime.h>

// LSTM B=65536, L=6, H=50, T=3, IN=3, FC 50->1 — fp16 MFMA, R14.
//
// R14 vs R10 (143us best; LDS pipe is top consumer: 16 b128 reads/wave/step)
// and R13 (199us; 1 wave/SIMD = no TLP, W didn't fit registers):
//  - Layer-entry x-precompute: x inputs for ALL T=3 steps are stable at layer
//    entry (prev layer's outputs, barrier-separated). Compute x-parts into
//    THREE acc sets xa0/xa1/xa2 (24 AGPR, statically indexed) once per layer,
//    during the h0-staging window where LDS/matrix pipes are idle.
//  - Per-step body shrinks to 4 ds_read_b128 + 4 h-MFMA + ACT + 2 b16 writes:
//    per-step LDS reads and MFMAs halve vs R10.
//  - Geometry: M=32, BLK=1024 (16 waves x 1 n-tile), ring-5 LDS = 23KB ->
//    2 blocks/CU = 32 waves = full occupancy. Frugal regs: W 16 + xa 24 +
//    cc 2 + temps ~16 <= 64 combined (launch_bounds(1024,8)); STEP keeps
//    only 2 frags in flight.
//  - Ring liveness with all-x-reads-at-entry verified: slots read at entry
//    (s2,s3,s4) are overwritten only at steps t=1,2 / next-layer h0, all
//    barrier-separated.
//  - Same per-value accumulation order (x s0, x s1, h s0, h s1) and ACT ops
//    -> bitwise-identical numerics (absmax 0.0009765625).
// Layout: gates^T = W*X^T, n = 4j+gate; lane (q,lm) holds all 4 gates of
// unit j = 4*ntg+q, samples mt*16+lm. One barrier per step + 1 per layer.

namespace {

constexpr int H  = 50;
constexpr int L  = 6;
constexpr int T  = 3;
constexpr int IN = 3;
constexpr int M  = 32;     // samples per block (2 m-tiles)
constexpr int BLK = 1024;  // 16 waves, 1 n-tile each
constexpr int ROWS = 72;   // _Float16 row stride (144 B)
constexpr int NSLOT = 5;   // LDS ring slots
constexpr int SLOT = M * ROWS;             // elements per slot (2304)

using half8  = __attribute__((ext_vector_type(8))) _Float16;
using half2v = __attribute__((ext_vector_type(2))) _Float16;
using f32x4  = __attribute__((ext_vector_type(4))) float;

__device__ __forceinline__ float rcp_(float x) { return __builtin_amdgcn_rcpf(x); }
__device__ __forceinline__ float ex2(float x)  { return __builtin_amdgcn_exp2f(x); }

// ---------------- prologue: pack fp16 A-fragments, prescaled ----------------
// frag id f = (l*4 + s)*16 + nt ; lane's frag: W[n=16*nt+(lam&15)][k=32*s+(lam>>4)*8+jj]
// Rows prescaled: gate g (n&3==2) by 2/ln2, others by 1/ln2 (bias included).
__global__ void wprep(const float* __restrict__ w_ih0, const float* __restrict__ w_ihL,
                      const float* __restrict__ w_hh,  const float* __restrict__ b_ih,
                      const float* __restrict__ b_hh,  _Float16* __restrict__ wbuf) {
  int t = blockIdx.x * 256 + threadIdx.x;
  if (t >= 384 * 64) return;
  int lam = t & 63, f = t >> 6;
  int nt = f & 15, s = (f >> 4) & 3, l = f >> 6;
  int n = nt * 16 + (lam & 15);
  int j = n >> 2, gate = n & 3, row = gate * 50 + j;  // PyTorch gate order i,f,g,o
  float scale = (gate == 2) ? 2.8853900817779268f : 1.4426950408889634f;
  _Float16 o8[8];
#pragma unroll
  for (int jj = 0; jj < 8; ++jj) {
    int k = s * 32 + (lam >> 4) * 8 + jj;
    float v = 0.f;
    if (j < H) {
      if (s < 2) {                       // x-part, k in [0,64)
        int ksz = (l == 0) ? IN : H;
        if (k < ksz) v = (l == 0) ? w_ih0[row * IN + k]
                                  : w_ihL[((size_t)(l - 1) * 200 + row) * H + k];
      } else {                           // h-part
        int kh = k - 64;
        if (kh < H)        v = w_hh[((size_t)l * 200 + row) * H + kh];
        else if (kh == 63) v = b_ih[l * 200 + row] + b_hh[l * 200 + row];  // bias
      }
    }
    o8[jj] = (_Float16)(v * scale);
  }
  ((half8*)wbuf)[t] = *(half8*)o8;
}

// ---------------- main kernel ----------------
__global__ __launch_bounds__(BLK, 8)   // 8 waves/EU -> 64 combined regs, 2 blocks/CU
void lstm_mfma(const float* __restrict__ x,   const float* __restrict__ h0,
               const float* __restrict__ c0,  const float* __restrict__ fc_w,
               const float* __restrict__ fc_b, const _Float16* __restrict__ wbuf,
               float* __restrict__ out, int B) {
  const int tid = threadIdx.x;
  const int lam = tid & 63;
  const int q   = lam >> 4;
  const int lm  = lam & 15;
  const int bbase = blockIdx.x * M;
  const int w   = __builtin_amdgcn_readfirstlane(tid >> 6);
  const int ntg = __builtin_amdgcn_readfirstlane((w + blockIdx.x) & 15);  // pad-wave rotation
  const bool live = (ntg <= 12);            // tiles 13..15 are pure padding (j>=52)
  const int j = 4 * ntg + q;                // unit this lane owns (4 gates in acc regs)

  __shared__ __align__(16) _Float16 ys[NSLOT][M][ROWS];   // 23040 B

  // ---- once-only invariant: cols [50,62]=0, col 63=1.0 in ALL slots.
  //      (h/h0/x writes only touch k<50 -> holds forever) ----
  if (tid < NSLOT * M) {
    _Float16* row = &ys[0][0][0] + (size_t)tid * ROWS;
#pragma unroll
    for (int z = 0; z < 6; ++z)
      *(unsigned int*)(row + 50 + 2 * z) = 0u;            // cols 50..61
    half2v pb; pb[0] = (_Float16)0.f; pb[1] = (_Float16)1.f;
    *(half2v*)(row + 62) = pb;                            // 62=0, 63=1.0
  }
  // ---- x staging into slots 2,3,4 (= layer-0 s2,s3,s4): k<3 data, [3,32)=0 --
  if (tid < T * M) {                         // 96 threads, one (t,m) row each
    const int t = tid >> 5, m = tid & 31;
    const float* xs = x + (size_t)(bbase + m) * (IN * T) + t;
    _Float16* row = &ys[2 + t][m][0];
    half2v p0; p0[0] = (_Float16)xs[0]; p0[1] = (_Float16)xs[3];
    half2v p1; p1[0] = (_Float16)xs[6]; p1[1] = (_Float16)0.f;
    *(half2v*)(row)     = p0;
    *(half2v*)(row + 2) = p1;
#pragma unroll
    for (int z = 0; z < 7; ++z)              // k in [4,32) := 0 (layer-0 slab-0 pad)
      *(unsigned long long*)(row + 4 + 4 * z) = 0ull;
  }
  __syncthreads();

  float cc[2];
  f32x4 xa0[2], xa1[2], xa2[2];              // per-step acc sets (24 acc regs)
  half8 W4[4];                               // [kslab] — 16 regs
  const f32x4 z4 = {0.f, 0.f, 0.f, 0.f};

  // per-lane LDS read base: row lm, element offset q*8; slot/mt/slab are imm
  const _Float16* rbase = &ys[0][lm][q * 8];

// ---- macros (literal args -> static indexing, imm LDS offsets) ----
#define XPART(acc, slot) do {                                                  \
    half8 X0a = *(const half8*)(rbase + (slot) * SLOT);                        \
    half8 X0b = *(const half8*)(rbase + (slot) * SLOT + 16 * ROWS);            \
    acc[0] = __builtin_amdgcn_mfma_f32_16x16x32_f16(W4[0], X0a, z4, 0, 0, 0);  \
    acc[1] = __builtin_amdgcn_mfma_f32_16x16x32_f16(W4[0], X0b, z4, 0, 0, 0);  \
    if (l > 0) {  /* layer-0 slab 1 is all-zero W: skip */                     \
      half8 X1a = *(const half8*)(rbase + (slot) * SLOT + 32);                 \
      half8 X1b = *(const half8*)(rbase + (slot) * SLOT + 16 * ROWS + 32);     \
      acc[0] = __builtin_amdgcn_mfma_f32_16x16x32_f16(W4[1], X1a, acc[0], 0, 0, 0); \
      acc[1] = __builtin_amdgcn_mfma_f32_16x16x32_f16(W4[1], X1b, acc[1], 0, 0, 0); \
    }                                                                          \
  } while (0)
#define ACT1(acc, mt, sot) do {                                                \
    const float ig = rcp_(1.f + ex2(-acc[mt][0]));                             \
    const float fg = rcp_(1.f + ex2(-acc[mt][1]));                             \
    const float gg = 2.f * rcp_(1.f + ex2(-acc[mt][2])) - 1.f;                 \
    const float og = rcp_(1.f + ex2(-acc[mt][3]));                             \
    const float cv = fg * cc[mt] + ig * gg;                                    \
    cc[mt] = cv;                                                               \
    const float tc = 2.f * rcp_(1.f + ex2(-2.8853900817779268f * cv)) - 1.f;   \
    if (j < H)                                /* pad cols & k63 stay intact */ \
      ys[sot][(mt) * 16 + lm][j] = (_Float16)(og * tc);                        \
  } while (0)
#define STEP(acc, shs, sot) do {                                               \
    half8 Hf0a = *(const half8*)(rbase + (shs) * SLOT);                        \
    half8 Hf0b = *(const half8*)(rbase + (shs) * SLOT + 16 * ROWS);            \
    acc[0] = __builtin_amdgcn_mfma_f32_16x16x32_f16(W4[2], Hf0a, acc[0], 0, 0, 0); \
    acc[1] = __builtin_amdgcn_mfma_f32_16x16x32_f16(W4[2], Hf0b, acc[1], 0, 0, 0); \
    half8 Hf1a = *(const half8*)(rbase + (shs) * SLOT + 32);                   \
    half8 Hf1b = *(const half8*)(rbase + (shs) * SLOT + 16 * ROWS + 32);       \
    acc[0] = __builtin_amdgcn_mfma_f32_16x16x32_f16(W4[3], Hf1a, acc[0], 0, 0, 0); \
    acc[1] = __builtin_amdgcn_mfma_f32_16x16x32_f16(W4[3], Hf1b, acc[1], 0, 0, 0); \
    ACT1(acc, 0, sot);                                                         \
    ACT1(acc, 1, sot);                                                         \
  } while (0)

#pragma unroll
  for (int l = 0; l < L; ++l) {
    // ring slots, compile-time under full unroll
    const int sh0 = (4 * l) % 5;             // h0 / h-source t=0
    const int s1 = (sh0 + 1) % 5;            // out[0]
    const int s2 = (sh0 + 2) % 5;            // out[1] = x[0]
    const int s3 = (sh0 + 3) % 5;            // out[2] = x[1]
    const int s4 = (sh0 + 4) % 5;            // x[2]

    if (live) {
      // ---- c0 straight to registers ----
      cc[0] = (j < H) ? c0[((size_t)l * B + bbase + lm) * H + j] : 0.f;
      cc[1] = (j < H) ? c0[((size_t)l * B + bbase + 16 + lm) * H + j] : 0.f;
      // ---- W fragments for this layer (4 coalesced dwordx4) ----
#pragma unroll
      for (int s = 0; s < 4; ++s)
        W4[s] = ((const half8*)wbuf)[((l * 4 + s) * 16 + ntg) * 64 + lam];
      // ---- x-parts for ALL T steps (inputs stable since prev barrier) ----
      XPART(xa0, s2);
      XPART(xa1, s3);
      XPART(xa2, s4);
    }
    // ---- stage h0 into slot sh0, pair-packed (32 rows x 25 pairs) ----
    {
      const int mg = tid >> 5, kpl = tid & 31;           // 32 threads per row
      if (kpl < 25) {
        float2 v = *(const float2*)(h0 + ((size_t)l * B + bbase + mg) * H + 2 * kpl);
        half2v pv; pv[0] = (_Float16)v.x; pv[1] = (_Float16)v.y;
        *(half2v*)(&ys[sh0][mg][2 * kpl]) = pv;
      }
    }
    __syncthreads();

    // ---- T steps: 4 ds_read + 4 h-MFMA + ACT + 2 b16 writes each ----
    if (live) STEP(xa0, sh0, s1);
    __syncthreads();
    if (live) STEP(xa1, s1, s2);
    __syncthreads();
    if (live) STEP(xa2, s2, s3);
    __syncthreads();
  }
#undef XPART
#undef ACT1
#undef STEP

  // ---- fc tail: out[b] = fc_w · h_last + fc_b ----
  // final h slot = (4*(L-1)+T)%5 = 23%5 = 3
  if (tid < 8 * M) {
    int m = tid >> 3, strip = tid & 7;
    float part = 0.f;
#pragma unroll
    for (int jj = 0; jj < 7; ++jj) {
      int jf = strip + 8 * jj;
      if (jf < H) part += fc_w[jf] * (float)ys[3][m][jf];
    }
    part += __shfl_xor(part, 4);
    part += __shfl_xor(part, 2);
    part += __shfl_xor(part, 1);
    if (strip == 0) out[bbase + m] = part + fc_b[0];
  }
}

}  // namespace

extern "C" void kernel_launch(void* const* d_in, const int* in_sizes, int n_in,
                              void* d_out, int out_size, void* d_ws, size_t ws_size,
                              hipStream_t stream) {
  const float* x     = (const float*)d_in[0];
  const float* h0    = (const float*)d_in[1];
  const float* c0    = (const float*)d_in[2];
  const float* w_ih0 = (const float*)d_in[3];
  const float* w_ih  = (const float*)d_in[4];
  const float* w_hh  = (const float*)d_in[5];
  const float* b_ih  = (const float*)d_in[6];
  const float* b_hh  = (const float*)d_in[7];
  const float* fc_w  = (const float*)d_in[8];
  const float* fc_b  = (const float*)d_in[9];
  float* out         = (float*)d_out;

  const int B = in_sizes[0] / (IN * T);  // 65536
  _Float16* wbuf = (_Float16*)d_ws;      // 384 frags * 64 lanes * 16 B = 393 KB

  wprep<<<(384 * 64 + 255) / 256, 256, 0, stream>>>(w_ih0, w_ih, w_hh, b_ih, b_hh, wbuf);
  lstm_mfma<<<B / M, BLK, 0, stream>>>(x, h0, c0, fc_w, fc_b, wbuf, out, B);
}

// Round 8
// 268.372 us; speedup vs baseline: 1.1853x; 1.0442x over previous
//
#include <hip/hip_runtime.h>

// LSTM B=65536, L=6, H=50, T=3, IN=3, FC 50->1 — fp16 MFMA, R15.
//
// R15 = R10 (143us, best) + anti-phase stagger of co-resident blocks.
// Evidence across R8/R10/R12/R14: wall pinned 143-156us, VALUBusy pinned
// 43-47% while occupancy 41-81%, LDS volume 6x, interval count 2x varied.
// => work-rate-bound with a ~2.2x idle multiplier: within each barrier
// interval, LDS head -> MFMA -> ACT tail serialize, and co-resident blocks
// (same start, same period) stay phase-locked so neither fills the other's
// bubbles. LDS(~50%) + VALU(45%) + MFMA(16%) are on DIFFERENT pipes and can
// overlap if de-phased.
//  - Stagger: after staging barrier, read HW_ID.TG_ID (threadgroup slot id,
//    bits 19:16 — differs between the 2 co-resident blocks on a CU, uniform
//    within a block); odd slots s_sleep ~3584 cyc (~half step interval).
//    Identical periods keep the pair anti-phased thereafter.
//  - Benign failure modes: TG_ID uniform-constant -> no stagger (R10 repeat);
//    per-wave garbage -> first barrier re-syncs (one-time delay only).
//  - Everything else byte-identical to R10 -> absmax 0.0009765625.

namespace {

constexpr int H  = 50;
constexpr int L  = 6;
constexpr int T  = 3;
constexpr int IN = 3;
constexpr int M  = 64;     // samples per block (4 m-tiles)
constexpr int BLK = 1024;  // 16 waves, 1 n-tile each
constexpr int ROWS = 72;   // _Float16 row stride (144 B)
constexpr int NSLOT = 5;   // LDS ring slots

using half8  = __attribute__((ext_vector_type(8))) _Float16;
using half2v = __attribute__((ext_vector_type(2))) _Float16;
using f32x4  = __attribute__((ext_vector_type(4))) float;

__device__ __forceinline__ float rcp_(float x) { return __builtin_amdgcn_rcpf(x); }
__device__ __forceinline__ float ex2(float x)  { return __builtin_amdgcn_exp2f(x); }

// ---------------- prologue: pack fp16 A-fragments, prescaled ----------------
// frag id f = (l*4 + s)*16 + nt ; lane's frag: W[n=16*nt+(lam&15)][k=32*s+(lam>>4)*8+jj]
// Rows prescaled: gate g (n&3==2) by 2/ln2, others by 1/ln2 (bias included).
__global__ void wprep(const float* __restrict__ w_ih0, const float* __restrict__ w_ihL,
                      const float* __restrict__ w_hh,  const float* __restrict__ b_ih,
                      const float* __restrict__ b_hh,  _Float16* __restrict__ wbuf) {
  int t = blockIdx.x * 256 + threadIdx.x;
  if (t >= 384 * 64) return;
  int lam = t & 63, f = t >> 6;
  int nt = f & 15, s = (f >> 4) & 3, l = f >> 6;
  int n = nt * 16 + (lam & 15);
  int j = n >> 2, gate = n & 3, row = gate * 50 + j;  // PyTorch gate order i,f,g,o
  float scale = (gate == 2) ? 2.8853900817779268f : 1.4426950408889634f;
  _Float16 o8[8];
#pragma unroll
  for (int jj = 0; jj < 8; ++jj) {
    int k = s * 32 + (lam >> 4) * 8 + jj;
    float v = 0.f;
    if (j < H) {
      if (s < 2) {                       // x-part, k in [0,64)
        int ksz = (l == 0) ? IN : H;
        if (k < ksz) v = (l == 0) ? w_ih0[row * IN + k]
                                  : w_ihL[((size_t)(l - 1) * 200 + row) * H + k];
      } else {                           // h-part
        int kh = k - 64;
        if (kh < H)        v = w_hh[((size_t)l * 200 + row) * H + kh];
        else if (kh == 63) v = b_ih[l * 200 + row] + b_hh[l * 200 + row];  // bias
      }
    }
    o8[jj] = (_Float16)(v * scale);
  }
  ((half8*)wbuf)[t] = *(half8*)o8;
}

// ---------------- main kernel ----------------
__global__ __launch_bounds__(BLK, 8)   // 8 waves/EU -> cap 64 regs, 2 blocks/CU
void lstm_mfma(const float* __restrict__ x,   const float* __restrict__ h0,
               const float* __restrict__ c0,  const float* __restrict__ fc_w,
               const float* __restrict__ fc_b, const _Float16* __restrict__ wbuf,
               float* __restrict__ out, int B) {
  const int tid = threadIdx.x;
  const int lam = tid & 63;
  const int q   = lam >> 4;
  const int lm  = lam & 15;
  const int bbase = blockIdx.x * M;
  const int w   = __builtin_amdgcn_readfirstlane(tid >> 6);
  const int ntg = __builtin_amdgcn_readfirstlane((w + blockIdx.x) & 15);  // pad-wave rotation
  const bool live = (ntg <= 12);            // tiles 13..15 are pure padding (j>=52)
  const int j = 4 * ntg + q;                // unit index this lane owns (gates in acc regs)

  __shared__ __align__(16) _Float16 ys[NSLOT][M][ROWS];   // 46080 B

  // ---- once-only invariant: cols [50,62]=0, col 63=1.0 in ALL slots.
  //      (h-writes touch j<50 only; h0/x staging touch k<50 -> holds forever)
  if (tid < NSLOT * M) {
    _Float16* row = &ys[0][0][0] + (size_t)tid * ROWS;
#pragma unroll
    for (int z = 0; z < 6; ++z)
      *(unsigned int*)(row + 50 + 2 * z) = 0u;            // cols 50..61
    half2v pb; pb[0] = (_Float16)0.f; pb[1] = (_Float16)1.f;
    *(half2v*)(row + 62) = pb;                            // 62=0, 63=1.0
  }
  // ---- x staging into slots 2,3,4 (= sigma(-1,t)): k<3 data, [3,32) zero ----
  if (tid < T * M) {
    const int t = tid >> 6, m = tid & 63;
    const float* xs = x + (size_t)(bbase + m) * (IN * T) + t;
    _Float16* row = &ys[2 + t][m][0];
    half2v p0; p0[0] = (_Float16)xs[0]; p0[1] = (_Float16)xs[3];
    half2v p1; p1[0] = (_Float16)xs[6]; p1[1] = (_Float16)0.f;
    *(half2v*)(row)     = p0;
    *(half2v*)(row + 2) = p1;
#pragma unroll
    for (int z = 0; z < 7; ++z)              // k in [4,32) := 0 (layer-0 slab-0 pad)
      *(unsigned long long*)(row + 4 + 4 * z) = 0ull;
  }
  __syncthreads();

  // ---- anti-phase stagger: odd threadgroup-slot blocks start ~half interval
  //      late; co-resident pair stays anti-phased (identical periods). ----
  {
    // HW_ID (id=4) TG_ID field: offset 16, size 4 -> imm (3<<11)|(16<<6)|4
    const unsigned tg = __builtin_amdgcn_s_getreg((3u << 11) | (16u << 6) | 4u);
    if (tg & 1u) __builtin_amdgcn_s_sleep(56);   // ~3584 clocks
  }

  float cc[4];
  f32x4 xa[4];                               // x-part acc; h-part accumulates in
  half8 W4[4];                               // 4 k-slabs — 16 regs
  const f32x4 z4 = {0.f, 0.f, 0.f, 0.f};
  int b = 0;                                 // h0 slot for layer l = (4l)%5

  for (int l = 0; l < L; ++l) {
    const int sh0 = b;
    int s1 = b + 1; if (s1 >= NSLOT) s1 -= NSLOT;   // out[0]
    int s2 = b + 2; if (s2 >= NSLOT) s2 -= NSLOT;   // out[1] = x[0]
    int s3 = b + 3; if (s3 >= NSLOT) s3 -= NSLOT;   // out[2] = x[1]
    int s4 = b + 4; if (s4 >= NSLOT) s4 -= NSLOT;   // x[2]

    if (live) {
      // ---- c0 straight to registers ----
#pragma unroll
      for (int mt = 0; mt < 4; ++mt)
        cc[mt] = (j < H)
            ? c0[((size_t)l * B + bbase + mt * 16 + lm) * H + j] : 0.f;
      // ---- W fragments for this layer (coalesced dwordx4) ----
#pragma unroll
      for (int s = 0; s < 4; ++s)
        W4[s] = ((const half8*)wbuf)[((l * 4 + s) * 16 + ntg) * 64 + lam];
      // ---- x-part of t=0 from x[0]=s2 (stable since prev barrier) ----
#pragma unroll
      for (int mt = 0; mt < 4; ++mt) {
        half8 X0 = *(const half8*)(&ys[s2][mt * 16 + lm][q * 8]);
        xa[mt] = __builtin_amdgcn_mfma_f32_16x16x32_f16(W4[0], X0, z4, 0, 0, 0);
      }
      if (l > 0) {                           // layer-0 slab 1 is all-zero W: skip
#pragma unroll
        for (int mt = 0; mt < 4; ++mt) {
          half8 X1 = *(const half8*)(&ys[s2][mt * 16 + lm][32 + q * 8]);
          xa[mt] = __builtin_amdgcn_mfma_f32_16x16x32_f16(W4[1], X1, xa[mt], 0, 0, 0);
        }
      }
    }
    // ---- stage h0 into slot sh0, pair-packed, all 1024 threads ----
    {
      const int mg = tid >> 4, kpl = tid & 15;           // 16 threads per row
      const float* hp = h0 + ((size_t)l * B + bbase + mg) * H + 2 * kpl;
      _Float16* dp = &ys[sh0][mg][2 * kpl];
      float2 v = *(const float2*)(hp);
      half2v pv; pv[0] = (_Float16)v.x; pv[1] = (_Float16)v.y;
      *(half2v*)dp = pv;
      if (kpl < 9) {                                     // pairs 16..24 (k 32..49)
        float2 v2 = *(const float2*)(hp + 32);
        half2v p2; p2[0] = (_Float16)v2.x; p2[1] = (_Float16)v2.y;
        *(half2v*)(dp + 32) = p2;
      }
    }
    __syncthreads();

#pragma unroll
    for (int t = 0; t < T; ++t) {
      const int shs = (t == 0) ? sh0 : ((t == 1) ? s1 : s2);  // h-source slot
      const int sot = (t == 0) ? s1  : ((t == 1) ? s2 : s3);  // h-dest slot
      const int sxt = (t == 0) ? s3  : s4;                    // x-prefetch slot
      if (live) {
        // ---- h-part: slabs 2,3 accumulate onto prefetched x-part ----
#pragma unroll
        for (int s = 0; s < 2; ++s)
#pragma unroll
          for (int mt = 0; mt < 4; ++mt) {
            half8 Hf = *(const half8*)(&ys[shs][mt * 16 + lm][s * 32 + q * 8]);
            xa[mt] = __builtin_amdgcn_mfma_f32_16x16x32_f16(W4[2 + s], Hf, xa[mt], 0, 0, 0);
          }
        // ---- activations: prescaled gates -> sigm = rcp(1+exp2(-g)) ----
#pragma unroll
        for (int mt = 0; mt < 4; ++mt) {
          const float ig = rcp_(1.f + ex2(-xa[mt][0]));
          const float fg = rcp_(1.f + ex2(-xa[mt][1]));
          const float gg = 2.f * rcp_(1.f + ex2(-xa[mt][2])) - 1.f;
          const float og = rcp_(1.f + ex2(-xa[mt][3]));
          const float cv = fg * cc[mt] + ig * gg;
          cc[mt] = cv;
          const float tc = 2.f * rcp_(1.f + ex2(-2.8853900817779268f * cv)) - 1.f;
          if (j < H)                          // pad cols (and k63=1.0) stay intact
            ys[sot][mt * 16 + lm][j] = (_Float16)(og * tc);
        }
        // ---- x-part prefetch for t+1 (slot stable; fills barrier window) ----
        if (t < T - 1) {
#pragma unroll
          for (int mt = 0; mt < 4; ++mt) {
            half8 X0 = *(const half8*)(&ys[sxt][mt * 16 + lm][q * 8]);
            xa[mt] = __builtin_amdgcn_mfma_f32_16x16x32_f16(W4[0], X0, z4, 0, 0, 0);
          }
          if (l > 0) {
#pragma unroll
            for (int mt = 0; mt < 4; ++mt) {
              half8 X1 = *(const half8*)(&ys[sxt][mt * 16 + lm][32 + q * 8]);
              xa[mt] = __builtin_amdgcn_mfma_f32_16x16x32_f16(W4[1], X1, xa[mt], 0, 0, 0);
            }
          }
        }
      }
      __syncthreads();   // h_t (and, at t=T-1, layer output) visible
    }
    b = (b == 0) ? (NSLOT - 1) : b - 1;      // (4(l+1))%5 = (b+4)%5 = b-1 mod 5
  }

  // ---- fc tail: out[b] = fc_w · h_last + fc_b ----
  // final h slot = sigma(L-1, T-1) = (4*(L-1)+T)%5 = (20+3)%5 = 3
  if (tid < 512) {
    int m = tid >> 3, strip = tid & 7;
    float part = 0.f;
#pragma unroll
    for (int jj = 0; jj < 7; ++jj) {
      int jf = strip + 8 * jj;
      if (jf < H) part += fc_w[jf] * (float)ys[3][m][jf];
    }
    part += __shfl_xor(part, 4);
    part += __shfl_xor(part, 2);
    part += __shfl_xor(part, 1);
    if (strip == 0) out[bbase + m] = part + fc_b[0];
  }
}

}  // namespace

extern "C" void kernel_launch(void* const* d_in, const int* in_sizes, int n_in,
                              void* d_out, int out_size, void* d_ws, size_t ws_size,
                              hipStream_t stream) {
  const float* x     = (const float*)d_in[0];
  const float* h0    = (const float*)d_in[1];
  const float* c0    = (const float*)d_in[2];
  const float* w_ih0 = (const float*)d_in[3];
  const float* w_ih  = (const float*)d_in[4];
  const float* w_hh  = (const float*)d_in[5];
  const float* b_ih  = (const float*)d_in[6];
  const float* b_hh  = (const float*)d_in[7];
  const float* fc_w  = (const float*)d_in[8];
  const float* fc_b  = (const float*)d_in[9];
  float* out         = (float*)d_out;

  const int B = in_sizes[0] / (IN * T);  // 65536
  _Float16* wbuf = (_Float16*)d_ws;      // 384 frags * 64 lanes * 16 B = 393 KB

  wprep<<<(384 * 64 + 255) / 256, 256, 0, stream>>>(w_ih0, w_ih, w_hh, b_ih, b_hh, wbuf);
  lstm_mfma<<<B / M, BLK, 0, stream>>>(x, h0, c0, fc_w, fc_b, wbuf, out, B);
}

// Round 9
// 252.520 us; speedup vs baseline: 1.2597x; 1.0628x over previous
//
#include <hip/hip_runtime.h>

// LSTM B=65536, L=6, H=50, T=3, IN=3, FC 50->1 — fp16 MFMA, R16.
//
// R16 vs R10/R15 (143us; interval = LDS-service + trans/VALU + ~1.2k fixed,
// little overlap; stagger null): cut serial volume + interval count.
//  - 7-trans ACT (was 10): merged reciprocals:
//      c = [cc*(1+zi)(1+zg) + (1-zg)(1+zf)] * rcp((1+zf)(1+zi)(1+zg))
//      h = (1-zc) * rcp((1+zc)(1+zo)),  z* = exp2(-prescaled gate)
//    5 exp2 + 2 rcp. Triple product <= ~1e14 (gates bounded ~|12| prescaled)
//    -> no overflow; added rel err ~1e-6 << fp16 quantum.
//  - Entry barrier eliminated (24 -> 19 barriers/block): h0(l+1) staged into
//    s4 DURING step t=2 (s4 dead there: last read t=1 x-prefetch, next read
//    l+1 t=0, barrier-separated). W/c0/x-part-t0 of l+1 run right after t2's
//    barrier (inputs s1 stable since l's t0; s4 just staged).
//  - s_sleep stagger removed (R15 null).
// Layout: gates^T = W*X^T, n = 4j+gate; lane (q,lm) holds all 4 gates of
// unit j = 4*ntg+q (lane-local c/h update). M=64, BLK=1024, 16 waves x
// 1 n-tile, ring-5 LDS 46KB, 2 blocks/CU, ~48 combined regs.

namespace {

constexpr int H  = 50;
constexpr int L  = 6;
constexpr int T  = 3;
constexpr int IN = 3;
constexpr int M  = 64;     // samples per block (4 m-tiles)
constexpr int BLK = 1024;  // 16 waves, 1 n-tile each
constexpr int ROWS = 72;   // _Float16 row stride (144 B)
constexpr int NSLOT = 5;   // LDS ring slots

using half8  = __attribute__((ext_vector_type(8))) _Float16;
using half2v = __attribute__((ext_vector_type(2))) _Float16;
using f32x4  = __attribute__((ext_vector_type(4))) float;

__device__ __forceinline__ float rcp_(float x) { return __builtin_amdgcn_rcpf(x); }
__device__ __forceinline__ float ex2(float x)  { return __builtin_amdgcn_exp2f(x); }

// ---------------- prologue: pack fp16 A-fragments, prescaled ----------------
// frag id f = (l*4 + s)*16 + nt ; lane's frag: W[n=16*nt+(lam&15)][k=32*s+(lam>>4)*8+jj]
// Rows prescaled: gate g (n&3==2) by 2/ln2, others by 1/ln2 (bias included).
__global__ void wprep(const float* __restrict__ w_ih0, const float* __restrict__ w_ihL,
                      const float* __restrict__ w_hh,  const float* __restrict__ b_ih,
                      const float* __restrict__ b_hh,  _Float16* __restrict__ wbuf) {
  int t = blockIdx.x * 256 + threadIdx.x;
  if (t >= 384 * 64) return;
  int lam = t & 63, f = t >> 6;
  int nt = f & 15, s = (f >> 4) & 3, l = f >> 6;
  int n = nt * 16 + (lam & 15);
  int j = n >> 2, gate = n & 3, row = gate * 50 + j;  // PyTorch gate order i,f,g,o
  float scale = (gate == 2) ? 2.8853900817779268f : 1.4426950408889634f;
  _Float16 o8[8];
#pragma unroll
  for (int jj = 0; jj < 8; ++jj) {
    int k = s * 32 + (lam >> 4) * 8 + jj;
    float v = 0.f;
    if (j < H) {
      if (s < 2) {                       // x-part, k in [0,64)
        int ksz = (l == 0) ? IN : H;
        if (k < ksz) v = (l == 0) ? w_ih0[row * IN + k]
                                  : w_ihL[((size_t)(l - 1) * 200 + row) * H + k];
      } else {                           // h-part
        int kh = k - 64;
        if (kh < H)        v = w_hh[((size_t)l * 200 + row) * H + kh];
        else if (kh == 63) v = b_ih[l * 200 + row] + b_hh[l * 200 + row];  // bias
      }
    }
    o8[jj] = (_Float16)(v * scale);
  }
  ((half8*)wbuf)[t] = *(half8*)o8;
}

// ---------------- main kernel ----------------
__global__ __launch_bounds__(BLK, 8)   // 8 waves/EU -> cap 64 regs, 2 blocks/CU
void lstm_mfma(const float* __restrict__ x,   const float* __restrict__ h0,
               const float* __restrict__ c0,  const float* __restrict__ fc_w,
               const float* __restrict__ fc_b, const _Float16* __restrict__ wbuf,
               float* __restrict__ out, int B) {
  const int tid = threadIdx.x;
  const int lam = tid & 63;
  const int q   = lam >> 4;
  const int lm  = lam & 15;
  const int bbase = blockIdx.x * M;
  const int w   = __builtin_amdgcn_readfirstlane(tid >> 6);
  const int ntg = __builtin_amdgcn_readfirstlane((w + blockIdx.x) & 15);  // pad-wave rotation
  const bool live = (ntg <= 12);            // tiles 13..15 are pure padding (j>=52)
  const int j = 4 * ntg + q;                // unit index this lane owns (gates in acc regs)

  __shared__ __align__(16) _Float16 ys[NSLOT][M][ROWS];   // 46080 B

  // ---- once-only invariant: cols [50,62]=0, col 63=1.0 in ALL slots ----
  if (tid < NSLOT * M) {
    _Float16* row = &ys[0][0][0] + (size_t)tid * ROWS;
#pragma unroll
    for (int z = 0; z < 6; ++z)
      *(unsigned int*)(row + 50 + 2 * z) = 0u;            // cols 50..61
    half2v pb; pb[0] = (_Float16)0.f; pb[1] = (_Float16)1.f;
    *(half2v*)(row + 62) = pb;                            // 62=0, 63=1.0
  }
  // ---- x staging into slots 2,3,4: k<3 data, [3,32) zero ----
  if (tid < T * M) {
    const int t = tid >> 6, m = tid & 63;
    const float* xs = x + (size_t)(bbase + m) * (IN * T) + t;
    _Float16* row = &ys[2 + t][m][0];
    half2v p0; p0[0] = (_Float16)xs[0]; p0[1] = (_Float16)xs[3];
    half2v p1; p1[0] = (_Float16)xs[6]; p1[1] = (_Float16)0.f;
    *(half2v*)(row)     = p0;
    *(half2v*)(row + 2) = p1;
#pragma unroll
    for (int z = 0; z < 7; ++z)              // k in [4,32) := 0 (layer-0 slab-0 pad)
      *(unsigned long long*)(row + 4 + 4 * z) = 0ull;
  }
  // ---- h0 for layer 0 into slot 0 (pair-packed, all threads) ----
  {
    const int mg = tid >> 4, kpl = tid & 15;             // 16 threads per row
    const float* hp = h0 + ((size_t)bbase + mg) * H + 2 * kpl;
    _Float16* dp = &ys[0][mg][2 * kpl];
    float2 v = *(const float2*)(hp);
    half2v pv; pv[0] = (_Float16)v.x; pv[1] = (_Float16)v.y;
    *(half2v*)dp = pv;
    if (kpl < 9) {                                       // pairs 16..24 (k 32..49)
      float2 v2 = *(const float2*)(hp + 32);
      half2v p2; p2[0] = (_Float16)v2.x; p2[1] = (_Float16)v2.y;
      *(half2v*)(dp + 32) = p2;
    }
  }
  __syncthreads();

  float cc[4];
  f32x4 xa[4];                               // x-part acc; h-part accumulates in
  half8 W4[4];                               // 4 k-slabs — 16 regs
  const f32x4 z4 = {0.f, 0.f, 0.f, 0.f};
  int b = 0;                                 // h0 slot for layer l = (4l)%5

// ---- 7-trans activation (merged reciprocals), literal mt -> static idx ----
#define ACT1(mt, sot_) do {                                                    \
    const float zi = ex2(-xa[mt][0]);                                          \
    const float zf = ex2(-xa[mt][1]);                                          \
    const float zg = ex2(-xa[mt][2]);                                          \
    const float zo = ex2(-xa[mt][3]);                                          \
    const float pi_ = 1.f + zi, pf_ = 1.f + zf, pg_ = 1.f + zg, po_ = 1.f + zo;\
    const float t1 = pi_ * pg_;                                                \
    const float r1 = rcp_(t1 * pf_);                                           \
    const float cv = (cc[mt] * t1 + (1.f - zg) * pf_) * r1;                    \
    cc[mt] = cv;                                                               \
    const float zc = ex2(-2.8853900817779268f * cv);                           \
    const float pc_ = 1.f + zc;                                                \
    const float hv = (1.f - zc) * rcp_(pc_ * po_);                             \
    if (j < H)                                /* pad cols & k63 stay intact */ \
      ys[sot_][(mt) * 16 + lm][j] = (_Float16)hv;                              \
  } while (0)

  for (int l = 0; l < L; ++l) {
    const int sh0 = b;
    int s1 = b + 1; if (s1 >= NSLOT) s1 -= NSLOT;   // out[0]
    int s2 = b + 2; if (s2 >= NSLOT) s2 -= NSLOT;   // out[1] = x[0]
    int s3 = b + 3; if (s3 >= NSLOT) s3 -= NSLOT;   // out[2] = x[1]
    int s4 = b + 4; if (s4 >= NSLOT) s4 -= NSLOT;   // x[2]; h0(l+1) staged at t2

    // ---- layer entry, NO barrier: inputs stable since l-1's t2 barrier ----
    if (live) {
      // c0 straight to registers
#pragma unroll
      for (int mt = 0; mt < 4; ++mt)
        cc[mt] = (j < H)
            ? c0[((size_t)l * B + bbase + mt * 16 + lm) * H + j] : 0.f;
      // W fragments for this layer (coalesced dwordx4, L2-hot)
#pragma unroll
      for (int s = 0; s < 4; ++s)
        W4[s] = ((const half8*)wbuf)[((l * 4 + s) * 16 + ntg) * 64 + lam];
      // x-part of t=0 from x[0]=s2 (stable since prev barrier)
#pragma unroll
      for (int mt = 0; mt < 4; ++mt) {
        half8 X0 = *(const half8*)(&ys[s2][mt * 16 + lm][q * 8]);
        xa[mt] = __builtin_amdgcn_mfma_f32_16x16x32_f16(W4[0], X0, z4, 0, 0, 0);
      }
      if (l > 0) {                           // layer-0 slab 1 is all-zero W: skip
#pragma unroll
        for (int mt = 0; mt < 4; ++mt) {
          half8 X1 = *(const half8*)(&ys[s2][mt * 16 + lm][32 + q * 8]);
          xa[mt] = __builtin_amdgcn_mfma_f32_16x16x32_f16(W4[1], X1, xa[mt], 0, 0, 0);
        }
      }
    }

#pragma unroll
    for (int t = 0; t < T; ++t) {
      const int shs = (t == 0) ? sh0 : ((t == 1) ? s1 : s2);  // h-source slot
      const int sot = (t == 0) ? s1  : ((t == 1) ? s2 : s3);  // h-dest slot
      const int sxt = (t == 0) ? s3  : s4;                    // x-prefetch slot
      if (live) {
        // ---- h-part: slabs 2,3 accumulate onto prefetched x-part ----
#pragma unroll
        for (int s = 0; s < 2; ++s)
#pragma unroll
          for (int mt = 0; mt < 4; ++mt) {
            half8 Hf = *(const half8*)(&ys[shs][mt * 16 + lm][s * 32 + q * 8]);
            xa[mt] = __builtin_amdgcn_mfma_f32_16x16x32_f16(W4[2 + s], Hf, xa[mt], 0, 0, 0);
          }
        // ---- activations (7-trans) ----
        ACT1(0, sot); ACT1(1, sot); ACT1(2, sot); ACT1(3, sot);
        // ---- x-part prefetch for t+1 (slot stable; fills barrier window) ----
        if (t < T - 1) {
#pragma unroll
          for (int mt = 0; mt < 4; ++mt) {
            half8 X0 = *(const half8*)(&ys[sxt][mt * 16 + lm][q * 8]);
            xa[mt] = __builtin_amdgcn_mfma_f32_16x16x32_f16(W4[0], X0, z4, 0, 0, 0);
          }
          if (l > 0) {
#pragma unroll
            for (int mt = 0; mt < 4; ++mt) {
              half8 X1 = *(const half8*)(&ys[sxt][mt * 16 + lm][32 + q * 8]);
              xa[mt] = __builtin_amdgcn_mfma_f32_16x16x32_f16(W4[1], X1, xa[mt], 0, 0, 0);
            }
          }
        }
      }
      // ---- at t=2: stage h0(l+1) into s4 (dead slot: last read t=1 prefetch,
      //      next read l+1 t=0 — both barrier-separated). All threads. ----
      if (t == T - 1 && l < L - 1) {
        const int mg = tid >> 4, kpl = tid & 15;
        const float* hp = h0 + (((size_t)l + 1) * B + bbase + mg) * H + 2 * kpl;
        _Float16* dp = &ys[s4][mg][2 * kpl];
        float2 v = *(const float2*)(hp);
        half2v pv; pv[0] = (_Float16)v.x; pv[1] = (_Float16)v.y;
        *(half2v*)dp = pv;
        if (kpl < 9) {
          float2 v2 = *(const float2*)(hp + 32);
          half2v p2; p2[0] = (_Float16)v2.x; p2[1] = (_Float16)v2.y;
          *(half2v*)(dp + 32) = p2;
        }
      }
      __syncthreads();   // h_t (and, at t=T-1, layer output + h0') visible
    }
    b = (b == 0) ? (NSLOT - 1) : b - 1;      // (4(l+1))%5 = (b+4)%5 = b-1 mod 5
  }
#undef ACT1

  // ---- fc tail: out[b] = fc_w · h_last + fc_b ----
  // final h slot = sigma(L-1, T-1) = (4*(L-1)+T)%5 = (20+3)%5 = 3
  if (tid < 512) {
    int m = tid >> 3, strip = tid & 7;
    float part = 0.f;
#pragma unroll
    for (int jj = 0; jj < 7; ++jj) {
      int jf = strip + 8 * jj;
      if (jf < H) part += fc_w[jf] * (float)ys[3][m][jf];
    }
    part += __shfl_xor(part, 4);
    part += __shfl_xor(part, 2);
    part += __shfl_xor(part, 1);
    if (strip == 0) out[bbase + m] = part + fc_b[0];
  }
}

}  // namespace

extern "C" void kernel_launch(void* const* d_in, const int* in_sizes, int n_in,
                              void* d_out, int out_size, void* d_ws, size_t ws_size,
                              hipStream_t stream) {
  const float* x     = (const float*)d_in[0];
  const float* h0    = (const float*)d_in[1];
  const float* c0    = (const float*)d_in[2];
  const float* w_ih0 = (const float*)d_in[3];
  const float* w_ih  = (const float*)d_in[4];
  const float* w_hh  = (const float*)d_in[5];
  const float* b_ih  = (const float*)d_in[6];
  const float* b_hh  = (const float*)d_in[7];
  const float* fc_w  = (const float*)d_in[8];
  const float* fc_b  = (const float*)d_in[9];
  float* out         = (float*)d_out;

  const int B = in_sizes[0] / (IN * T);  // 65536
  _Float16* wbuf = (_Float16*)d_ws;      // 384 frags * 64 lanes * 16 B = 393 KB

  wprep<<<(384 * 64 + 255) / 256, 256, 0, stream>>>(w_ih0, w_ih, w_hh, b_ih, b_hh, wbuf);
  lstm_mfma<<<B / M, BLK, 0, stream>>>(x, h0, c0, fc_w, fc_b, wbuf, out, B);
}